// Round 9
// baseline (4026.571 us; speedup 1.0000x reference)
//
#include <hip/hip_runtime.h>
#include <cstdint>
#include <cstddef>

#define BATCH 512
#define D_IN 64
#define D_MODEL 768
#define DEPTH 24
#define D_INNER 1536
#define D_STATE 16
#define D_CONV 4
#define DT_RANK 48
#define XDB_DIM 80
#define GRID 512
#define NTHREADS 256

// s_getreg imm for HW_REG_XCC_ID (id=20), offset 0, size 4 bits
#define XCC_GETREG_IMM (20 | (3 << 11))

// counter indices (u32), 128B line spacing
#define CTR_GCNT 0
#define CTR_GO   32
#define CTR_GBAR 64
#define CTR_GGEN 96
#define CTR_RANK 128   // + vx*32
#define CTR_XBAR 384   // + g*32
#define CTR_TOTAL 1024

typedef __bf16 bf16x8 __attribute__((ext_vector_type(8)));
typedef unsigned short ushortx8 __attribute__((ext_vector_type(8)));
typedef float f32x4 __attribute__((ext_vector_type(4)));
typedef unsigned short ushort_t;

#define XZW_N ((size_t)2 * D_INNER * D_MODEL)
#define OPW_N ((size_t)D_MODEL * D_INNER)
#define XZ_ALL ((long)DEPTH * (long)(XZW_N / 8))
#define OP_ALL ((long)DEPTH * (long)(OPW_N / 8))
#define AN_ALL ((long)DEPTH * D_INNER * D_STATE / 8)

struct Args {
    const float *x_t, *in_w, *in_b, *conv_state, *conv_w, *conv_b;
    const float *xproj_w, *dtproj_w, *dtproj_b, *Dvec, *ssm_state, *ln_g, *ln_b;
    float *h, *x, *g, *Aneg, *out;
    ushort_t *h_hi, *h_lo, *y_hi, *y_lo;
    ushort_t *xzw_hi, *xzw_lo, *opw_hi, *opw_lo;
    unsigned *ctr;
};

__device__ __forceinline__ float sigmoidf_(float v) { return 1.f / (1.f + __expf(-v)); }

__device__ __forceinline__ void split1(float f, unsigned short& h, unsigned short& l) {
    unsigned int u = __float_as_uint(f);
    unsigned int uh = u & 0xffff0000u;
    h = (unsigned short)(uh >> 16);
    float r = f - __uint_as_float(uh);
    l = (unsigned short)(__float_as_uint(r) >> 16);
}

__device__ __forceinline__ void split8(const float* s, ushort_t* hi, ushort_t* lo) {
    float4 A4 = *(const float4*)s;
    float4 B4 = *(const float4*)(s + 4);
    float f[8] = {A4.x, A4.y, A4.z, A4.w, B4.x, B4.y, B4.z, B4.w};
    ushortx8 h, l;
#pragma unroll
    for (int j = 0; j < 8; ++j) {
        unsigned short hh, ll;
        split1(f[j], hh, ll);
        h[j] = hh; l[j] = ll;
    }
    *(ushortx8*)hi = h;
    *(ushortx8*)lo = l;
}

// ======== standalone prep kernels (separate launches = free coherence) ======
__global__ __launch_bounds__(64) void k_init(unsigned* ctr) {
    for (int i = threadIdx.x; i < CTR_TOTAL; i += 64) ctr[i] = 0u;
}

__global__ __launch_bounds__(256) void k_prep(
    const float* __restrict__ xz_w, const float* __restrict__ op_w,
    const float* __restrict__ A_log,
    ushort_t* __restrict__ xzw_hi, ushort_t* __restrict__ xzw_lo,
    ushort_t* __restrict__ opw_hi, ushort_t* __restrict__ opw_lo,
    float* __restrict__ Aneg)
{
    const long total = XZ_ALL + OP_ALL + AN_ALL;
    long gg = (long)blockIdx.x * 256 + threadIdx.x;
    const long stride = (long)gridDim.x * 256;
    for (; gg < total; gg += stride) {
        if (gg < XZ_ALL) {
            split8(xz_w + gg * 8, xzw_hi + gg * 8, xzw_lo + gg * 8);
        } else if (gg < XZ_ALL + OP_ALL) {
            const long r = gg - XZ_ALL;
            split8(op_w + r * 8, opw_hi + r * 8, opw_lo + r * 8);
        } else {
            const long r = gg - XZ_ALL - OP_ALL;
            const float* s = A_log + r * 8;
            float* d = Aneg + r * 8;
#pragma unroll
            for (int j = 0; j < 8; ++j) d[j] = -__expf(s[j]);
        }
    }
}

// ======== device phase functions (g = row-group 0..7, rk = rank in group) ===

// in_proj fp32 GEMM tile: rows g*64, cols rk*64 (rk<12)
__device__ void dev_inproj(const Args& a, int g, int rk, char* smem) {
    float (*As)[68] = (float (*)[68])smem;
    float (*Ws)[68] = (float (*)[68])(smem + 16 * 68 * 4);
    const int tid = threadIdx.x;
    const int tx = tid & 15, ty = tid >> 4;
    const int bm0 = g * 64, bn0 = rk * 64;
    float acc[4][4] = {};
    for (int k0 = 0; k0 < D_IN; k0 += 16) {
        int r = tid >> 2, c = (tid & 3) << 2;
        float4 a4 = *(const float4*)(a.x_t + (size_t)(bm0 + r) * D_IN + k0 + c);
        As[c + 0][r] = a4.x; As[c + 1][r] = a4.y;
        As[c + 2][r] = a4.z; As[c + 3][r] = a4.w;
        float4 w4 = *(const float4*)(a.in_w + (size_t)(bn0 + r) * D_IN + k0 + c);
        Ws[c + 0][r] = w4.x; Ws[c + 1][r] = w4.y;
        Ws[c + 2][r] = w4.z; Ws[c + 3][r] = w4.w;
        __syncthreads();
#pragma unroll
        for (int kk = 0; kk < 16; ++kk) {
            float af[4], wf[4];
#pragma unroll
            for (int i = 0; i < 4; ++i) af[i] = As[kk][ty * 4 + i];
#pragma unroll
            for (int j = 0; j < 4; ++j) wf[j] = Ws[kk][tx * 4 + j];
#pragma unroll
            for (int i = 0; i < 4; ++i)
#pragma unroll
                for (int j = 0; j < 4; ++j) acc[i][j] += af[i] * wf[j];
        }
        __syncthreads();
    }
#pragma unroll
    for (int i = 0; i < 4; ++i) {
        const int bb = bm0 + ty * 4 + i;
#pragma unroll
        for (int j = 0; j < 4; ++j) {
            const int n = bn0 + tx * 4 + j;
            float v = acc[i][j] + a.in_b[n];
            const size_t idx = (size_t)bb * D_MODEL + n;
            unsigned short hh, ll;
            split1(v, hh, ll);
            a.h_hi[idx] = hh;
            a.h_lo[idx] = ll;
        }
    }
}

// bf16x3 MFMA GEMM 64x64 tile. MODE 0: xz (rk<48, K=768, conv/silu epilogue).
// MODE 1: outproj (rk<12, K=1536) -> h fp32 + h planes.
template<int MODE>
__device__ void dev_gemm(const Args& a, int l, int g, int rk, char* smem) {
    constexpr int K = (MODE == 0) ? D_MODEL : D_INNER;
    constexpr int nk = K / 32;
    const int bm0 = g * 64, bn0 = rk * 64;
    const ushort_t *Ahi, *Alo, *Whi, *Wlo;
    if (MODE == 0) {
        Ahi = a.h_hi; Alo = a.h_lo;
        Whi = a.xzw_hi + (size_t)l * XZW_N;
        Wlo = a.xzw_lo + (size_t)l * XZW_N;
    } else {
        Ahi = a.y_hi; Alo = a.y_lo;
        Whi = a.opw_hi + (size_t)l * OPW_N;
        Wlo = a.opw_lo + (size_t)l * OPW_N;
    }
    unsigned short* As = (unsigned short*)smem;              // [2][4096]
    unsigned short* Bs = (unsigned short*)(smem + 16384);    // [2][4096]

    const int t = threadIdx.x;
    const int sr = t >> 2, s0 = t & 3;
    const int lane = t & 63, wv = t >> 6;
    const int wm = wv >> 1, wn = wv & 1;
    const int ln15 = lane & 15, kq = lane >> 4;

    const ushort_t* Ah = Ahi + (size_t)(bm0 + sr) * K + s0 * 8;
    const ushort_t* Al = Alo + (size_t)(bm0 + sr) * K + s0 * 8;
    const ushort_t* Wh = Whi + (size_t)(bn0 + sr) * K + s0 * 8;
    const ushort_t* Wl = Wlo + (size_t)(bn0 + sr) * K + s0 * 8;

    f32x4 acc[2][2];
#pragma unroll
    for (int m = 0; m < 2; ++m)
#pragma unroll
        for (int n = 0; n < 2; ++n) acc[m][n] = (f32x4){0.f, 0.f, 0.f, 0.f};

    const int sw = sr & 7;
    auto stage = [&](ushortx8 hi, ushortx8 lo, unsigned short* S) {
        *(ushortx8*)&S[sr * 64 + ((s0 ^ sw) << 3)] = hi;
        *(ushortx8*)&S[sr * 64 + (((s0 + 4) ^ sw) << 3)] = lo;
    };

    ushortx8 pah = *(const ushortx8*)Ah;
    ushortx8 pal = *(const ushortx8*)Al;
    ushortx8 pwh = *(const ushortx8*)Wh;
    ushortx8 pwl = *(const ushortx8*)Wl;
    stage(pah, pal, As);
    stage(pwh, pwl, Bs);

    for (int kb = 0; kb < nk; ++kb) {
        __syncthreads();
        const int cur = kb & 1;
        if (kb + 1 < nk) {
            const int ko = (kb + 1) << 5;
            pah = *(const ushortx8*)(Ah + ko);
            pal = *(const ushortx8*)(Al + ko);
            pwh = *(const ushortx8*)(Wh + ko);
            pwl = *(const ushortx8*)(Wl + ko);
        }
        bf16x8 ah[2], al2[2], bh[2], bl[2];
#pragma unroll
        for (int m = 0; m < 2; ++m) {
            const int rr = wm * 32 + m * 16 + ln15;
            const int base = cur * 4096 + rr * 64;
            const int rs = rr & 7;
            ah[m]  = __builtin_bit_cast(bf16x8, *(ushortx8*)&As[base + ((kq ^ rs) << 3)]);
            al2[m] = __builtin_bit_cast(bf16x8, *(ushortx8*)&As[base + (((kq + 4) ^ rs) << 3)]);
        }
#pragma unroll
        for (int n = 0; n < 2; ++n) {
            const int rr = wn * 32 + n * 16 + ln15;
            const int base = cur * 4096 + rr * 64;
            const int rs = rr & 7;
            bh[n] = __builtin_bit_cast(bf16x8, *(ushortx8*)&Bs[base + ((kq ^ rs) << 3)]);
            bl[n] = __builtin_bit_cast(bf16x8, *(ushortx8*)&Bs[base + (((kq + 4) ^ rs) << 3)]);
        }
#pragma unroll
        for (int m = 0; m < 2; ++m)
#pragma unroll
            for (int n = 0; n < 2; ++n) {
                acc[m][n] = __builtin_amdgcn_mfma_f32_16x16x32_bf16(ah[m],  bh[n], acc[m][n], 0, 0, 0);
                acc[m][n] = __builtin_amdgcn_mfma_f32_16x16x32_bf16(ah[m],  bl[n], acc[m][n], 0, 0, 0);
                acc[m][n] = __builtin_amdgcn_mfma_f32_16x16x32_bf16(al2[m], bh[n], acc[m][n], 0, 0, 0);
            }
        if (kb + 1 < nk) {
            stage(pah, pal, As + (cur ^ 1) * 4096);
            stage(pwh, pwl, Bs + (cur ^ 1) * 4096);
        }
    }

#pragma unroll
    for (int m = 0; m < 2; ++m) {
#pragma unroll
        for (int n = 0; n < 2; ++n) {
            const int col = bn0 + wn * 32 + n * 16 + ln15;
            const int row0 = bm0 + wm * 32 + m * 16 + kq * 4;
            f32x4 v = acc[m][n];
            if (MODE == 0) {
                const float* csl = a.conv_state + (size_t)l * BATCH * D_INNER * D_CONV;
                const float* cwl = a.conv_w + (size_t)l * D_INNER * D_CONV;
                const float* cbl = a.conv_b + (size_t)l * D_INNER;
                if (col < D_INNER) {
                    const float4 cwv = *(const float4*)(cwl + (size_t)col * 4);
                    const float cbv = cbl[col];
#pragma unroll
                    for (int j = 0; j < 4; ++j) {
                        const int row = row0 + j;
                        const float4 csv = *(const float4*)(csl + ((size_t)row * D_INNER + col) * 4);
                        float cc = csv.y * cwv.x + csv.z * cwv.y + csv.w * cwv.z
                                 + v[j] * cwv.w + cbv;
                        a.x[(size_t)row * D_INNER + col] = cc * sigmoidf_(cc);
                    }
                } else {
#pragma unroll
                    for (int j = 0; j < 4; ++j) {
                        float zv = v[j];
                        a.g[(size_t)(row0 + j) * D_INNER + (col - D_INNER)] = zv * sigmoidf_(zv);
                    }
                }
            } else {
#pragma unroll
                for (int j = 0; j < 4; ++j) {
                    const size_t idx = (size_t)(row0 + j) * D_MODEL + col;
                    float val = v[j];
                    a.h[idx] = val;
                    unsigned short hh, ll;
                    split1(val, hh, ll);
                    a.h_hi[idx] = hh;
                    a.h_lo[idx] = ll;
                }
            }
        }
    }
}

// fused xproj + dt + softplus + SSM + gate; rows g*64+rk*2, +1 (rk<32)
__device__ void dev_bc(const Args& a, int l, int g, int rk, char* smem) {
    float* xs0 = (float*)smem;
    float* xs1 = xs0 + D_INNER;
    float* xdb0 = xs1 + D_INNER;
    float* xdb1 = xdb0 + XDB_DIM;
    const int tid = threadIdx.x;
    const int b0 = g * 64 + rk * 2, b1 = b0 + 1;
    const float* xpl = a.xproj_w + (size_t)l * XDB_DIM * D_INNER;
    const float* dwl = a.dtproj_w + (size_t)l * D_INNER * DT_RANK;
    const float* dbl = a.dtproj_b + (size_t)l * D_INNER;
    const float* anl = a.Aneg + (size_t)l * D_INNER * D_STATE;
    const float* dpl = a.Dvec + (size_t)l * D_INNER;
    const float* ssl = a.ssm_state + (size_t)l * BATCH * D_INNER * D_STATE;

    {
        const float4* xr0 = (const float4*)(a.x + (size_t)b0 * D_INNER);
        const float4* xr1 = (const float4*)(a.x + (size_t)b1 * D_INNER);
        float4* d0 = (float4*)xs0; float4* d1 = (float4*)xs1;
        for (int i = tid; i < D_INNER / 4; i += NTHREADS) { d0[i] = xr0[i]; d1[i] = xr1[i]; }
    }
    __syncthreads();

    const int lane = tid & 63, wv = tid >> 6;
    const float4* xs40 = (const float4*)xs0;
    const float4* xs41 = (const float4*)xs1;
    for (int n = wv; n < XDB_DIM; n += 4) {
        const float4* wr = (const float4*)(xpl + (size_t)n * D_INNER);
        float s0 = 0.f, s1 = 0.f;
#pragma unroll
        for (int j = 0; j < D_INNER / 4 / 64; ++j) {
            float4 w = wr[lane + 64 * j];
            float4 u = xs40[lane + 64 * j];
            float4 q = xs41[lane + 64 * j];
            s0 += w.x * u.x + w.y * u.y + w.z * u.z + w.w * u.w;
            s1 += w.x * q.x + w.y * q.y + w.z * q.z + w.w * q.w;
        }
#pragma unroll
        for (int off = 32; off > 0; off >>= 1) { s0 += __shfl_xor(s0, off); s1 += __shfl_xor(s1, off); }
        if (lane == 0) { xdb0[n] = s0; xdb1[n] = s1; }
    }
    __syncthreads();

    float B0[16], C0[16], B1[16], C1[16];
#pragma unroll
    for (int n = 0; n < 16; ++n) {
        B0[n] = xdb0[DT_RANK + n]; C0[n] = xdb0[DT_RANK + 16 + n];
        B1[n] = xdb1[DT_RANK + n]; C1[n] = xdb1[DT_RANK + 16 + n];
    }

    for (int d = tid; d < D_INNER; d += NTHREADS) {
        const float4* dtw = (const float4*)(dwl + (size_t)d * DT_RANK);
        float s0 = 0.f, s1 = 0.f;
#pragma unroll
        for (int j = 0; j < DT_RANK / 4; ++j) {
            float4 w = dtw[j];
            s0 += w.x * xdb0[4*j] + w.y * xdb0[4*j+1] + w.z * xdb0[4*j+2] + w.w * xdb0[4*j+3];
            s1 += w.x * xdb1[4*j] + w.y * xdb1[4*j+1] + w.z * xdb1[4*j+2] + w.w * xdb1[4*j+3];
        }
        const float bb = dbl[d];
        s0 += bb; s1 += bb;
        float dt0 = fmaxf(s0, 0.f) + log1pf(__expf(-fabsf(s0)));
        float dt1 = fmaxf(s1, 0.f) + log1pf(__expf(-fabsf(s1)));
        const float xv0 = xs0[d], xv1 = xs1[d];
        const float dtx0 = dt0 * xv0, dtx1 = dt1 * xv1;
        const float4* anp = (const float4*)(anl + (size_t)d * D_STATE);
        const float4* sp0 = (const float4*)(ssl + ((size_t)b0 * D_INNER + d) * D_STATE);
        const float4* sp1 = (const float4*)(ssl + ((size_t)b1 * D_INNER + d) * D_STATE);
        float y0 = 0.f, y1 = 0.f;
#pragma unroll
        for (int q = 0; q < 4; ++q) {
            float4 an = anp[q];
            float4 u = sp0[q];
            float4 w = sp1[q];
            float e;
            e = __expf(dt0 * an.x); y0 += (u.x * e + dtx0 * B0[4*q+0]) * C0[4*q+0];
            e = __expf(dt0 * an.y); y0 += (u.y * e + dtx0 * B0[4*q+1]) * C0[4*q+1];
            e = __expf(dt0 * an.z); y0 += (u.z * e + dtx0 * B0[4*q+2]) * C0[4*q+2];
            e = __expf(dt0 * an.w); y0 += (u.w * e + dtx0 * B0[4*q+3]) * C0[4*q+3];
            e = __expf(dt1 * an.x); y1 += (w.x * e + dtx1 * B1[4*q+0]) * C1[4*q+0];
            e = __expf(dt1 * an.y); y1 += (w.y * e + dtx1 * B1[4*q+1]) * C1[4*q+1];
            e = __expf(dt1 * an.z); y1 += (w.z * e + dtx1 * B1[4*q+2]) * C1[4*q+2];
            e = __expf(dt1 * an.w); y1 += (w.w * e + dtx1 * B1[4*q+3]) * C1[4*q+3];
        }
        const float dv = dpl[d];
        y0 += dv * xv0; y1 += dv * xv1;
        const float o0 = y0 * a.g[(size_t)b0 * D_INNER + d];
        const float o1 = y1 * a.g[(size_t)b1 * D_INNER + d];
        unsigned short hh, ll;
        split1(o0, hh, ll);
        a.y_hi[(size_t)b0 * D_INNER + d] = hh; a.y_lo[(size_t)b0 * D_INNER + d] = ll;
        split1(o1, hh, ll);
        a.y_hi[(size_t)b1 * D_INNER + d] = hh; a.y_lo[(size_t)b1 * D_INNER + d] = ll;
    }
}

// LayerNorm, row g*64+rk
__device__ void dev_ln(const Args& a, int g, int rk, char* smem) {
    float* red = (float*)smem;
    const int tid = threadIdx.x;
    const int b = g * 64 + rk;
    float v[3];
#pragma unroll
    for (int j = 0; j < 3; ++j) v[j] = a.h[(size_t)b * D_MODEL + tid + j * 256];
    float s = v[0] + v[1] + v[2];
    float s2 = v[0] * v[0] + v[1] * v[1] + v[2] * v[2];
#pragma unroll
    for (int off = 32; off > 0; off >>= 1) {
        s += __shfl_xor(s, off);
        s2 += __shfl_xor(s2, off);
    }
    const int lane = tid & 63, wv = tid >> 6;
    if (lane == 0) { red[wv] = s; red[4 + wv] = s2; }
    __syncthreads();
    s = red[0] + red[1] + red[2] + red[3];
    s2 = red[4] + red[5] + red[6] + red[7];
    const float mu = s * (1.f / D_MODEL);
    const float var = s2 * (1.f / D_MODEL) - mu * mu;
    const float inv = 1.f / sqrtf(var + 1e-5f);
#pragma unroll
    for (int j = 0; j < 3; ++j) {
        int c = tid + j * 256;
        a.out[(size_t)b * D_MODEL + c] = (v[j] - mu) * inv * a.ln_g[c] + a.ln_b[c];
    }
}

// ================= persistent cooperative kernel =================
// 56KB static LDS caps occupancy at 2 blocks/CU -> 512 coop blocks place
// exactly 64 per XCD (pigeonhole). XCD x owns rows [64x,64x+64): all per-layer
// intermediates stay in one XCD's L2 -> per-XCD barriers need only an L1 inv.
// Runtime-verified; falls back to fence-based global barriers if violated.
__global__ __launch_bounds__(NTHREADS, 2) void persist(Args a) {
    __shared__ __align__(16) char smem[57344];
    __shared__ unsigned s_vx, s_rk, s_gr, s_mode;
    if (threadIdx.x == 0) {
        unsigned vx = __builtin_amdgcn_s_getreg(XCC_GETREG_IMM) & 7u;
        unsigned rk = __hip_atomic_fetch_add(&a.ctr[CTR_RANK + vx * 32], 1u,
                                             __ATOMIC_RELAXED, __HIP_MEMORY_SCOPE_AGENT);
        asm volatile("s_waitcnt vmcnt(0)" ::: "memory");  // rank-add lands before arrival
        unsigned gr = __hip_atomic_fetch_add(&a.ctr[CTR_GCNT], 1u,
                                             __ATOMIC_RELAXED, __HIP_MEMORY_SCOPE_AGENT);
        if (gr == GRID - 1) {
            bool good = true;
            for (int v = 0; v < 8; ++v)
                good = good && (__hip_atomic_load(&a.ctr[CTR_RANK + v * 32],
                        __ATOMIC_RELAXED, __HIP_MEMORY_SCOPE_AGENT) == 64u);
            __hip_atomic_store(&a.ctr[CTR_GO], good ? 3u : 2u,
                               __ATOMIC_RELAXED, __HIP_MEMORY_SCOPE_AGENT);
        }
        unsigned go;
        while ((go = __hip_atomic_load(&a.ctr[CTR_GO], __ATOMIC_RELAXED,
                                       __HIP_MEMORY_SCOPE_AGENT)) < 2u)
            __builtin_amdgcn_s_sleep(32);
        s_vx = vx; s_rk = rk; s_gr = gr; s_mode = go;
    }
    __syncthreads();
    const bool good = (s_mode == 3u);
    const int g  = good ? (int)s_vx : (int)(s_gr >> 6);
    const int rk = good ? (int)s_rk : (int)(s_gr & 63u);
    unsigned* xc = &a.ctr[CTR_XBAR + g * 32];
    unsigned xtgt = 0, ggen = 0;

    auto bar = [&]() {
        __syncthreads();
        if (good) {
            xtgt += 64;
            if (threadIdx.x == 0) {
                __hip_atomic_fetch_add(xc, 1u, __ATOMIC_RELAXED, __HIP_MEMORY_SCOPE_AGENT);
                while (__hip_atomic_load(xc, __ATOMIC_RELAXED,
                                         __HIP_MEMORY_SCOPE_AGENT) < xtgt)
                    __builtin_amdgcn_s_sleep(32);
            }
            __syncthreads();
            asm volatile("buffer_inv sc0" ::: "memory");  // L1 only; L2 is XCD-shared
        } else {
            ggen += 1;
            if (threadIdx.x == 0) {
                __builtin_amdgcn_fence(__ATOMIC_RELEASE, "agent");
                unsigned old = __hip_atomic_fetch_add(&a.ctr[CTR_GBAR], 1u,
                        __ATOMIC_RELAXED, __HIP_MEMORY_SCOPE_AGENT);
                if (old == ggen * GRID - 1) {
                    __hip_atomic_store(&a.ctr[CTR_GGEN], ggen,
                            __ATOMIC_RELAXED, __HIP_MEMORY_SCOPE_AGENT);
                } else {
                    while (__hip_atomic_load(&a.ctr[CTR_GGEN], __ATOMIC_RELAXED,
                                             __HIP_MEMORY_SCOPE_AGENT) < ggen)
                        __builtin_amdgcn_s_sleep(32);
                }
                __builtin_amdgcn_fence(__ATOMIC_ACQUIRE, "agent");
            }
            __syncthreads();
        }
    };

    if (rk < 12) dev_inproj(a, g, rk, smem);
    bar();

    for (int l = 0; l < DEPTH; ++l) {
        if (rk < 48) dev_gemm<0>(a, l, g, rk, smem);
        bar();
        if (rk < 32) dev_bc(a, l, g, rk, smem);
        bar();
        if (rk < 12) dev_gemm<1>(a, l, g, rk, smem);
        bar();
    }
    dev_ln(a, g, rk, smem);
}

// ================= fallback wrappers (multi-kernel, r8-equivalent) ==========
__global__ __launch_bounds__(NTHREADS) void k_inproj(Args a) {
    __shared__ __align__(16) char smem[32768];
    dev_inproj(a, blockIdx.x / 12, blockIdx.x % 12, smem);
}
__global__ __launch_bounds__(NTHREADS) void k_xz(Args a, int l) {
    __shared__ __align__(16) char smem[32768];
    dev_gemm<0>(a, l, blockIdx.x / 48, blockIdx.x % 48, smem);
}
__global__ __launch_bounds__(NTHREADS) void k_bc(Args a, int l) {
    __shared__ __align__(16) char smem[32768];
    dev_bc(a, l, blockIdx.x / 32, blockIdx.x % 32, smem);
}
__global__ __launch_bounds__(NTHREADS) void k_op(Args a, int l) {
    __shared__ __align__(16) char smem[32768];
    dev_gemm<1>(a, l, blockIdx.x / 12, blockIdx.x % 12, smem);
}
__global__ __launch_bounds__(NTHREADS) void k_ln(Args a) {
    __shared__ __align__(16) char smem[32768];
    dev_ln(a, blockIdx.x / 64, blockIdx.x % 64, smem);
}

extern "C" void kernel_launch(void* const* d_in, const int* in_sizes, int n_in,
                              void* d_out, int out_size, void* d_ws, size_t ws_size,
                              hipStream_t stream)
{
    char* wsb = (char*)d_ws;
    unsigned* ctr = (unsigned*)wsb;                        // 4KB
    float* h    = (float*)(wsb + 4096);
    float* x    = h + (size_t)BATCH * D_MODEL;
    float* g    = x + (size_t)BATCH * D_INNER;
    float* Aneg = g + (size_t)BATCH * D_INNER;
    ushort_t* h_hi = (ushort_t*)(Aneg + (size_t)DEPTH * D_INNER * D_STATE);
    ushort_t* h_lo = h_hi + (size_t)BATCH * D_MODEL;
    ushort_t* y_hi = h_lo + (size_t)BATCH * D_MODEL;
    ushort_t* y_lo = y_hi + (size_t)BATCH * D_INNER;
    ushort_t* xzw_hi = y_lo + (size_t)BATCH * D_INNER;
    ushort_t* xzw_lo = xzw_hi + (size_t)DEPTH * XZW_N;
    ushort_t* opw_hi = xzw_lo + (size_t)DEPTH * XZW_N;
    ushort_t* opw_lo = opw_hi + (size_t)DEPTH * OPW_N;

    Args args;
    args.x_t        = (const float*)d_in[0];
    args.in_w       = (const float*)d_in[1];
    args.in_b       = (const float*)d_in[2];
    const float* xz_w      = (const float*)d_in[3];
    args.conv_w     = (const float*)d_in[4];
    args.conv_b     = (const float*)d_in[5];
    args.xproj_w    = (const float*)d_in[6];
    args.dtproj_w   = (const float*)d_in[7];
    args.dtproj_b   = (const float*)d_in[8];
    const float* A_log     = (const float*)d_in[9];
    args.Dvec       = (const float*)d_in[10];
    const float* outproj_w = (const float*)d_in[11];
    args.conv_state = (const float*)d_in[12];
    args.ssm_state  = (const float*)d_in[13];
    args.ln_g       = (const float*)d_in[14];
    args.ln_b       = (const float*)d_in[15];
    args.h = h; args.x = x; args.g = g; args.Aneg = Aneg;
    args.out = (float*)d_out;
    args.h_hi = h_hi; args.h_lo = h_lo; args.y_hi = y_hi; args.y_lo = y_lo;
    args.xzw_hi = xzw_hi; args.xzw_lo = xzw_lo;
    args.opw_hi = opw_hi; args.opw_lo = opw_lo;
    args.ctr = ctr;

    dim3 blk(NTHREADS);

    k_init<<<dim3(1), dim3(64), 0, stream>>>(ctr);
    k_prep<<<dim3(2048), blk, 0, stream>>>(
        xz_w, outproj_w, A_log, xzw_hi, xzw_lo, opw_hi, opw_lo, Aneg);

    void* kp[] = { &args };
    hipError_t e = hipLaunchCooperativeKernel((const void*)persist, dim3(GRID),
                                              dim3(NTHREADS), kp, 0, stream);
    if (e != hipSuccess) {
        (void)hipGetLastError();  // clear; fall back to proven multi-kernel path
        k_inproj<<<dim3(96), blk, 0, stream>>>(args);
        for (int l = 0; l < DEPTH; ++l) {
            k_xz<<<dim3(384), blk, 0, stream>>>(args, l);
            k_bc<<<dim3(256), blk, 0, stream>>>(args, l);
            k_op<<<dim3(96), blk, 0, stream>>>(args, l);
        }
        k_ln<<<dim3(512), blk, 0, stream>>>(args);
    }
}

// Round 10
// 3980.227 us; speedup vs baseline: 1.0116x; 1.0116x over previous
//
#include <hip/hip_runtime.h>
#include <cstdint>
#include <cstddef>

#define BATCH 512
#define D_IN 64
#define D_MODEL 768
#define DEPTH 24
#define D_INNER 1536
#define D_STATE 16
#define D_CONV 4
#define DT_RANK 48
#define XDB_DIM 80
#define GRID 512
#define NTHREADS 256

// s_getreg imm for HW_REG_XCC_ID (id=20), offset 0, size 4 bits
#define XCC_GETREG_IMM (20 | (3 << 11))

// counter indices (u32), 128B line spacing
#define CTR_GCNT 0
#define CTR_GO   32
#define CTR_GBAR 64
#define CTR_GGEN 96
#define CTR_RANK 128    // + vx*32   (8 lines)
#define CTR_GOX  384    // + g*32    (8 lines)
#define CTR_FLAG 1024   // + (g*64+rk)*32  (512 lines)
#define CTR_TOTAL (1024 + 512 * 32)

typedef __bf16 bf16x8 __attribute__((ext_vector_type(8)));
typedef unsigned short ushortx8 __attribute__((ext_vector_type(8)));
typedef float f32x4 __attribute__((ext_vector_type(4)));
typedef unsigned short ushort_t;

#define XZW_N ((size_t)2 * D_INNER * D_MODEL)
#define OPW_N ((size_t)D_MODEL * D_INNER)
#define XZ_ALL ((long)DEPTH * (long)(XZW_N / 8))
#define OP_ALL ((long)DEPTH * (long)(OPW_N / 8))
#define AN_ALL ((long)DEPTH * D_INNER * D_STATE / 8)

struct Args {
    const float *x_t, *in_w, *in_b, *conv_state, *conv_w, *conv_b;
    const float *xproj_w, *dtproj_w, *dtproj_b, *Dvec, *ssm_state, *ln_g, *ln_b;
    float *h, *x, *g, *Aneg, *out;
    ushort_t *h_hi, *h_lo, *y_hi, *y_lo;
    ushort_t *xzw_hi, *xzw_lo, *opw_hi, *opw_lo;
    unsigned *ctr;
};

__device__ __forceinline__ float sigmoidf_(float v) { return 1.f / (1.f + __expf(-v)); }

__device__ __forceinline__ void split1(float f, unsigned short& h, unsigned short& l) {
    unsigned int u = __float_as_uint(f);
    unsigned int uh = u & 0xffff0000u;
    h = (unsigned short)(uh >> 16);
    float r = f - __uint_as_float(uh);
    l = (unsigned short)(__float_as_uint(r) >> 16);
}

__device__ __forceinline__ void split8(const float* s, ushort_t* hi, ushort_t* lo) {
    float4 A4 = *(const float4*)s;
    float4 B4 = *(const float4*)(s + 4);
    float f[8] = {A4.x, A4.y, A4.z, A4.w, B4.x, B4.y, B4.z, B4.w};
    ushortx8 h, l;
#pragma unroll
    for (int j = 0; j < 8; ++j) {
        unsigned short hh, ll;
        split1(f[j], hh, ll);
        h[j] = hh; l[j] = ll;
    }
    *(ushortx8*)hi = h;
    *(ushortx8*)lo = l;
}

// ======== standalone prep kernels (separate launches = free coherence) ======
__global__ __launch_bounds__(256) void k_init(unsigned* ctr) {
    const int i = blockIdx.x * 256 + threadIdx.x;
    if (i < CTR_TOTAL) ctr[i] = 0u;
}

__global__ __launch_bounds__(256) void k_prep(
    const float* __restrict__ xz_w, const float* __restrict__ op_w,
    const float* __restrict__ A_log,
    ushort_t* __restrict__ xzw_hi, ushort_t* __restrict__ xzw_lo,
    ushort_t* __restrict__ opw_hi, ushort_t* __restrict__ opw_lo,
    float* __restrict__ Aneg)
{
    const long total = XZ_ALL + OP_ALL + AN_ALL;
    long gg = (long)blockIdx.x * 256 + threadIdx.x;
    const long stride = (long)gridDim.x * 256;
    for (; gg < total; gg += stride) {
        if (gg < XZ_ALL) {
            split8(xz_w + gg * 8, xzw_hi + gg * 8, xzw_lo + gg * 8);
        } else if (gg < XZ_ALL + OP_ALL) {
            const long r = gg - XZ_ALL;
            split8(op_w + r * 8, opw_hi + r * 8, opw_lo + r * 8);
        } else {
            const long r = gg - XZ_ALL - OP_ALL;
            const float* s = A_log + r * 8;
            float* d = Aneg + r * 8;
#pragma unroll
            for (int j = 0; j < 8; ++j) d[j] = -__expf(s[j]);
        }
    }
}

// ======== device phase functions (g = row-group 0..7, rk = rank in group) ===

__device__ void dev_inproj(const Args& a, int g, int rk, char* smem) {
    float (*As)[68] = (float (*)[68])smem;
    float (*Ws)[68] = (float (*)[68])(smem + 16 * 68 * 4);
    const int tid = threadIdx.x;
    const int tx = tid & 15, ty = tid >> 4;
    const int bm0 = g * 64, bn0 = rk * 64;
    float acc[4][4] = {};
    for (int k0 = 0; k0 < D_IN; k0 += 16) {
        int r = tid >> 2, c = (tid & 3) << 2;
        float4 a4 = *(const float4*)(a.x_t + (size_t)(bm0 + r) * D_IN + k0 + c);
        As[c + 0][r] = a4.x; As[c + 1][r] = a4.y;
        As[c + 2][r] = a4.z; As[c + 3][r] = a4.w;
        float4 w4 = *(const float4*)(a.in_w + (size_t)(bn0 + r) * D_IN + k0 + c);
        Ws[c + 0][r] = w4.x; Ws[c + 1][r] = w4.y;
        Ws[c + 2][r] = w4.z; Ws[c + 3][r] = w4.w;
        __syncthreads();
#pragma unroll
        for (int kk = 0; kk < 16; ++kk) {
            float af[4], wf[4];
#pragma unroll
            for (int i = 0; i < 4; ++i) af[i] = As[kk][ty * 4 + i];
#pragma unroll
            for (int j = 0; j < 4; ++j) wf[j] = Ws[kk][tx * 4 + j];
#pragma unroll
            for (int i = 0; i < 4; ++i)
#pragma unroll
                for (int j = 0; j < 4; ++j) acc[i][j] += af[i] * wf[j];
        }
        __syncthreads();
    }
#pragma unroll
    for (int i = 0; i < 4; ++i) {
        const int bb = bm0 + ty * 4 + i;
#pragma unroll
        for (int j = 0; j < 4; ++j) {
            const int n = bn0 + tx * 4 + j;
            float v = acc[i][j] + a.in_b[n];
            const size_t idx = (size_t)bb * D_MODEL + n;
            unsigned short hh, ll;
            split1(v, hh, ll);
            a.h_hi[idx] = hh;
            a.h_lo[idx] = ll;
        }
    }
}

// bf16x3 MFMA GEMM 64x64 tile. MODE 0: xz (rk<48, K=768, conv/silu epilogue).
// MODE 1: outproj (rk<12, K=1536) -> h fp32 + h planes.
template<int MODE>
__device__ void dev_gemm(const Args& a, int l, int g, int rk, char* smem) {
    constexpr int K = (MODE == 0) ? D_MODEL : D_INNER;
    constexpr int nk = K / 32;
    const int bm0 = g * 64, bn0 = rk * 64;
    const ushort_t *Ahi, *Alo, *Whi, *Wlo;
    if (MODE == 0) {
        Ahi = a.h_hi; Alo = a.h_lo;
        Whi = a.xzw_hi + (size_t)l * XZW_N;
        Wlo = a.xzw_lo + (size_t)l * XZW_N;
    } else {
        Ahi = a.y_hi; Alo = a.y_lo;
        Whi = a.opw_hi + (size_t)l * OPW_N;
        Wlo = a.opw_lo + (size_t)l * OPW_N;
    }
    unsigned short* As = (unsigned short*)smem;              // [2][4096]
    unsigned short* Bs = (unsigned short*)(smem + 16384);    // [2][4096]

    const int t = threadIdx.x;
    const int sr = t >> 2, s0 = t & 3;
    const int lane = t & 63, wv = t >> 6;
    const int wm = wv >> 1, wn = wv & 1;
    const int ln15 = lane & 15, kq = lane >> 4;

    const ushort_t* Ah = Ahi + (size_t)(bm0 + sr) * K + s0 * 8;
    const ushort_t* Al = Alo + (size_t)(bm0 + sr) * K + s0 * 8;
    const ushort_t* Wh = Whi + (size_t)(bn0 + sr) * K + s0 * 8;
    const ushort_t* Wl = Wlo + (size_t)(bn0 + sr) * K + s0 * 8;

    f32x4 acc[2][2];
#pragma unroll
    for (int m = 0; m < 2; ++m)
#pragma unroll
        for (int n = 0; n < 2; ++n) acc[m][n] = (f32x4){0.f, 0.f, 0.f, 0.f};

    const int sw = sr & 7;
    auto stage = [&](ushortx8 hi, ushortx8 lo, unsigned short* S) {
        *(ushortx8*)&S[sr * 64 + ((s0 ^ sw) << 3)] = hi;
        *(ushortx8*)&S[sr * 64 + (((s0 + 4) ^ sw) << 3)] = lo;
    };

    ushortx8 pah = *(const ushortx8*)Ah;
    ushortx8 pal = *(const ushortx8*)Al;
    ushortx8 pwh = *(const ushortx8*)Wh;
    ushortx8 pwl = *(const ushortx8*)Wl;
    stage(pah, pal, As);
    stage(pwh, pwl, Bs);

    for (int kb = 0; kb < nk; ++kb) {
        __syncthreads();
        const int cur = kb & 1;
        if (kb + 1 < nk) {
            const int ko = (kb + 1) << 5;
            pah = *(const ushortx8*)(Ah + ko);
            pal = *(const ushortx8*)(Al + ko);
            pwh = *(const ushortx8*)(Wh + ko);
            pwl = *(const ushortx8*)(Wl + ko);
        }
        bf16x8 ah[2], al2[2], bh[2], bl[2];
#pragma unroll
        for (int m = 0; m < 2; ++m) {
            const int rr = wm * 32 + m * 16 + ln15;
            const int base = cur * 4096 + rr * 64;
            const int rs = rr & 7;
            ah[m]  = __builtin_bit_cast(bf16x8, *(ushortx8*)&As[base + ((kq ^ rs) << 3)]);
            al2[m] = __builtin_bit_cast(bf16x8, *(ushortx8*)&As[base + (((kq + 4) ^ rs) << 3)]);
        }
#pragma unroll
        for (int n = 0; n < 2; ++n) {
            const int rr = wn * 32 + n * 16 + ln15;
            const int base = cur * 4096 + rr * 64;
            const int rs = rr & 7;
            bh[n] = __builtin_bit_cast(bf16x8, *(ushortx8*)&Bs[base + ((kq ^ rs) << 3)]);
            bl[n] = __builtin_bit_cast(bf16x8, *(ushortx8*)&Bs[base + (((kq + 4) ^ rs) << 3)]);
        }
#pragma unroll
        for (int m = 0; m < 2; ++m)
#pragma unroll
            for (int n = 0; n < 2; ++n) {
                acc[m][n] = __builtin_amdgcn_mfma_f32_16x16x32_bf16(ah[m],  bh[n], acc[m][n], 0, 0, 0);
                acc[m][n] = __builtin_amdgcn_mfma_f32_16x16x32_bf16(ah[m],  bl[n], acc[m][n], 0, 0, 0);
                acc[m][n] = __builtin_amdgcn_mfma_f32_16x16x32_bf16(al2[m], bh[n], acc[m][n], 0, 0, 0);
            }
        if (kb + 1 < nk) {
            stage(pah, pal, As + (cur ^ 1) * 4096);
            stage(pwh, pwl, Bs + (cur ^ 1) * 4096);
        }
    }

#pragma unroll
    for (int m = 0; m < 2; ++m) {
#pragma unroll
        for (int n = 0; n < 2; ++n) {
            const int col = bn0 + wn * 32 + n * 16 + ln15;
            const int row0 = bm0 + wm * 32 + m * 16 + kq * 4;
            f32x4 v = acc[m][n];
            if (MODE == 0) {
                const float* csl = a.conv_state + (size_t)l * BATCH * D_INNER * D_CONV;
                const float* cwl = a.conv_w + (size_t)l * D_INNER * D_CONV;
                const float* cbl = a.conv_b + (size_t)l * D_INNER;
                if (col < D_INNER) {
                    const float4 cwv = *(const float4*)(cwl + (size_t)col * 4);
                    const float cbv = cbl[col];
#pragma unroll
                    for (int j = 0; j < 4; ++j) {
                        const int row = row0 + j;
                        const float4 csv = *(const float4*)(csl + ((size_t)row * D_INNER + col) * 4);
                        float cc = csv.y * cwv.x + csv.z * cwv.y + csv.w * cwv.z
                                 + v[j] * cwv.w + cbv;
                        a.x[(size_t)row * D_INNER + col] = cc * sigmoidf_(cc);
                    }
                } else {
#pragma unroll
                    for (int j = 0; j < 4; ++j) {
                        float zv = v[j];
                        a.g[(size_t)(row0 + j) * D_INNER + (col - D_INNER)] = zv * sigmoidf_(zv);
                    }
                }
            } else {
#pragma unroll
                for (int j = 0; j < 4; ++j) {
                    const size_t idx = (size_t)(row0 + j) * D_MODEL + col;
                    float val = v[j];
                    a.h[idx] = val;
                    unsigned short hh, ll;
                    split1(val, hh, ll);
                    a.h_hi[idx] = hh;
                    a.h_lo[idx] = ll;
                }
            }
        }
    }
}

// fused xproj + dt + softplus + SSM + gate; rows g*64+rk*2, +1 (rk<32)
__device__ void dev_bc(const Args& a, int l, int g, int rk, char* smem) {
    float* xs0 = (float*)smem;
    float* xs1 = xs0 + D_INNER;
    float* xdb0 = xs1 + D_INNER;
    float* xdb1 = xdb0 + XDB_DIM;
    const int tid = threadIdx.x;
    const int b0 = g * 64 + rk * 2, b1 = b0 + 1;
    const float* xpl = a.xproj_w + (size_t)l * XDB_DIM * D_INNER;
    const float* dwl = a.dtproj_w + (size_t)l * D_INNER * DT_RANK;
    const float* dbl = a.dtproj_b + (size_t)l * D_INNER;
    const float* anl = a.Aneg + (size_t)l * D_INNER * D_STATE;
    const float* dpl = a.Dvec + (size_t)l * D_INNER;
    const float* ssl = a.ssm_state + (size_t)l * BATCH * D_INNER * D_STATE;

    {
        const float4* xr0 = (const float4*)(a.x + (size_t)b0 * D_INNER);
        const float4* xr1 = (const float4*)(a.x + (size_t)b1 * D_INNER);
        float4* d0 = (float4*)xs0; float4* d1 = (float4*)xs1;
        for (int i = tid; i < D_INNER / 4; i += NTHREADS) { d0[i] = xr0[i]; d1[i] = xr1[i]; }
    }
    __syncthreads();

    const int lane = tid & 63, wv = tid >> 6;
    const float4* xs40 = (const float4*)xs0;
    const float4* xs41 = (const float4*)xs1;
    for (int n = wv; n < XDB_DIM; n += 4) {
        const float4* wr = (const float4*)(xpl + (size_t)n * D_INNER);
        float s0 = 0.f, s1 = 0.f;
#pragma unroll
        for (int j = 0; j < D_INNER / 4 / 64; ++j) {
            float4 w = wr[lane + 64 * j];
            float4 u = xs40[lane + 64 * j];
            float4 q = xs41[lane + 64 * j];
            s0 += w.x * u.x + w.y * u.y + w.z * u.z + w.w * u.w;
            s1 += w.x * q.x + w.y * q.y + w.z * q.z + w.w * q.w;
        }
#pragma unroll
        for (int off = 32; off > 0; off >>= 1) { s0 += __shfl_xor(s0, off); s1 += __shfl_xor(s1, off); }
        if (lane == 0) { xdb0[n] = s0; xdb1[n] = s1; }
    }
    __syncthreads();

    float B0[16], C0[16], B1[16], C1[16];
#pragma unroll
    for (int n = 0; n < 16; ++n) {
        B0[n] = xdb0[DT_RANK + n]; C0[n] = xdb0[DT_RANK + 16 + n];
        B1[n] = xdb1[DT_RANK + n]; C1[n] = xdb1[DT_RANK + 16 + n];
    }

    for (int d = tid; d < D_INNER; d += NTHREADS) {
        const float4* dtw = (const float4*)(dwl + (size_t)d * DT_RANK);
        float s0 = 0.f, s1 = 0.f;
#pragma unroll
        for (int j = 0; j < DT_RANK / 4; ++j) {
            float4 w = dtw[j];
            s0 += w.x * xdb0[4*j] + w.y * xdb0[4*j+1] + w.z * xdb0[4*j+2] + w.w * xdb0[4*j+3];
            s1 += w.x * xdb1[4*j] + w.y * xdb1[4*j+1] + w.z * xdb1[4*j+2] + w.w * xdb1[4*j+3];
        }
        const float bb = dbl[d];
        s0 += bb; s1 += bb;
        float dt0 = fmaxf(s0, 0.f) + log1pf(__expf(-fabsf(s0)));
        float dt1 = fmaxf(s1, 0.f) + log1pf(__expf(-fabsf(s1)));
        const float xv0 = xs0[d], xv1 = xs1[d];
        const float dtx0 = dt0 * xv0, dtx1 = dt1 * xv1;
        const float4* anp = (const float4*)(anl + (size_t)d * D_STATE);
        const float4* sp0 = (const float4*)(ssl + ((size_t)b0 * D_INNER + d) * D_STATE);
        const float4* sp1 = (const float4*)(ssl + ((size_t)b1 * D_INNER + d) * D_STATE);
        float y0 = 0.f, y1 = 0.f;
#pragma unroll
        for (int q = 0; q < 4; ++q) {
            float4 an = anp[q];
            float4 u = sp0[q];
            float4 w = sp1[q];
            float e;
            e = __expf(dt0 * an.x); y0 += (u.x * e + dtx0 * B0[4*q+0]) * C0[4*q+0];
            e = __expf(dt0 * an.y); y0 += (u.y * e + dtx0 * B0[4*q+1]) * C0[4*q+1];
            e = __expf(dt0 * an.z); y0 += (u.z * e + dtx0 * B0[4*q+2]) * C0[4*q+2];
            e = __expf(dt0 * an.w); y0 += (u.w * e + dtx0 * B0[4*q+3]) * C0[4*q+3];
            e = __expf(dt1 * an.x); y1 += (w.x * e + dtx1 * B1[4*q+0]) * C1[4*q+0];
            e = __expf(dt1 * an.y); y1 += (w.y * e + dtx1 * B1[4*q+1]) * C1[4*q+1];
            e = __expf(dt1 * an.z); y1 += (w.z * e + dtx1 * B1[4*q+2]) * C1[4*q+2];
            e = __expf(dt1 * an.w); y1 += (w.w * e + dtx1 * B1[4*q+3]) * C1[4*q+3];
        }
        const float dv = dpl[d];
        y0 += dv * xv0; y1 += dv * xv1;
        const float o0 = y0 * a.g[(size_t)b0 * D_INNER + d];
        const float o1 = y1 * a.g[(size_t)b1 * D_INNER + d];
        unsigned short hh, ll;
        split1(o0, hh, ll);
        a.y_hi[(size_t)b0 * D_INNER + d] = hh; a.y_lo[(size_t)b0 * D_INNER + d] = ll;
        split1(o1, hh, ll);
        a.y_hi[(size_t)b1 * D_INNER + d] = hh; a.y_lo[(size_t)b1 * D_INNER + d] = ll;
    }
}

// LayerNorm, row g*64+rk
__device__ void dev_ln(const Args& a, int g, int rk, char* smem) {
    float* red = (float*)smem;
    const int tid = threadIdx.x;
    const int b = g * 64 + rk;
    float v[3];
#pragma unroll
    for (int j = 0; j < 3; ++j) v[j] = a.h[(size_t)b * D_MODEL + tid + j * 256];
    float s = v[0] + v[1] + v[2];
    float s2 = v[0] * v[0] + v[1] * v[1] + v[2] * v[2];
#pragma unroll
    for (int off = 32; off > 0; off >>= 1) {
        s += __shfl_xor(s, off);
        s2 += __shfl_xor(s2, off);
    }
    const int lane = tid & 63, wv = tid >> 6;
    if (lane == 0) { red[wv] = s; red[4 + wv] = s2; }
    __syncthreads();
    s = red[0] + red[1] + red[2] + red[3];
    s2 = red[4] + red[5] + red[6] + red[7];
    const float mu = s * (1.f / D_MODEL);
    const float var = s2 * (1.f / D_MODEL) - mu * mu;
    const float inv = 1.f / sqrtf(var + 1e-5f);
#pragma unroll
    for (int j = 0; j < 3; ++j) {
        int c = tid + j * 256;
        a.out[(size_t)b * D_MODEL + c] = (v[j] - mu) * inv * a.ln_g[c] + a.ln_b[c];
    }
}

// ================= persistent cooperative kernel =================
// XCD-local partition (rows per XCD, r9) + flag-array barrier: arrival is a
// STORE to the block's own 128B line (parallel, no RMW serialization — r9's
// 40us/barrier was N atomic-adds serializing on one MALL line at ~300ns each);
// rank-0's wave-0 scans all 64 flags with ONE 64-lane load per poll; release
// via a GO line; then buffer_inv sc0 (L1 only — data stays in XCD-shared L2).
__global__ __launch_bounds__(NTHREADS, 2) void persist(Args a) {
    __shared__ __align__(16) char smem[57344];
    __shared__ unsigned s_vx, s_rk, s_gr, s_mode;
    if (threadIdx.x == 0) {
        unsigned vx = __builtin_amdgcn_s_getreg(XCC_GETREG_IMM) & 7u;
        unsigned rk = __hip_atomic_fetch_add(&a.ctr[CTR_RANK + vx * 32], 1u,
                                             __ATOMIC_RELAXED, __HIP_MEMORY_SCOPE_AGENT);
        asm volatile("s_waitcnt vmcnt(0)" ::: "memory");  // rank-add lands before arrival
        unsigned gr = __hip_atomic_fetch_add(&a.ctr[CTR_GCNT], 1u,
                                             __ATOMIC_RELAXED, __HIP_MEMORY_SCOPE_AGENT);
        if (gr == GRID - 1) {
            bool good = true;
            for (int v = 0; v < 8; ++v)
                good = good && (__hip_atomic_load(&a.ctr[CTR_RANK + v * 32],
                        __ATOMIC_RELAXED, __HIP_MEMORY_SCOPE_AGENT) == 64u);
            __hip_atomic_store(&a.ctr[CTR_GO], good ? 3u : 2u,
                               __ATOMIC_RELAXED, __HIP_MEMORY_SCOPE_AGENT);
        }
        unsigned go;
        while ((go = __hip_atomic_load(&a.ctr[CTR_GO], __ATOMIC_RELAXED,
                                       __HIP_MEMORY_SCOPE_AGENT)) < 2u)
            __builtin_amdgcn_s_sleep(32);
        s_vx = vx; s_rk = rk; s_gr = gr; s_mode = go;
    }
    __syncthreads();
    const bool good = (s_mode == 3u);
    const int g  = good ? (int)s_vx : (int)(s_gr >> 6);
    const int rk = good ? (int)s_rk : (int)(s_gr & 63u);
    unsigned epoch = 0;

    auto bar = [&]() {
        ++epoch;
        __syncthreads();   // drains each wave's vmem (compiler emits vmcnt(0) before s_barrier)
        if (good) {
            if (threadIdx.x == 0)
                __hip_atomic_store(&a.ctr[CTR_FLAG + (g * 64 + rk) * 32], epoch,
                                   __ATOMIC_RELAXED, __HIP_MEMORY_SCOPE_AGENT);
            if (rk == 0) {
                if (threadIdx.x < 64) {
                    unsigned* fp = &a.ctr[CTR_FLAG + (g * 64 + threadIdx.x) * 32];
                    while (__hip_atomic_load(fp, __ATOMIC_RELAXED,
                                             __HIP_MEMORY_SCOPE_AGENT) < epoch)
                        __builtin_amdgcn_s_sleep(1);
                    if (threadIdx.x == 0)
                        __hip_atomic_store(&a.ctr[CTR_GOX + g * 32], epoch,
                                           __ATOMIC_RELAXED, __HIP_MEMORY_SCOPE_AGENT);
                }
            } else if (threadIdx.x == 0) {
                while (__hip_atomic_load(&a.ctr[CTR_GOX + g * 32], __ATOMIC_RELAXED,
                                         __HIP_MEMORY_SCOPE_AGENT) < epoch)
                    __builtin_amdgcn_s_sleep(4);
            }
            __syncthreads();
            asm volatile("buffer_inv sc0" ::: "memory");  // L1 only; L2 is XCD-shared
        } else {
            if (threadIdx.x == 0) {
                __builtin_amdgcn_fence(__ATOMIC_RELEASE, "agent");
                unsigned old = __hip_atomic_fetch_add(&a.ctr[CTR_GBAR], 1u,
                        __ATOMIC_RELAXED, __HIP_MEMORY_SCOPE_AGENT);
                if (old == epoch * GRID - 1) {
                    __hip_atomic_store(&a.ctr[CTR_GGEN], epoch,
                            __ATOMIC_RELAXED, __HIP_MEMORY_SCOPE_AGENT);
                } else {
                    while (__hip_atomic_load(&a.ctr[CTR_GGEN], __ATOMIC_RELAXED,
                                             __HIP_MEMORY_SCOPE_AGENT) < epoch)
                        __builtin_amdgcn_s_sleep(32);
                }
                __builtin_amdgcn_fence(__ATOMIC_ACQUIRE, "agent");
            }
            __syncthreads();
        }
    };

    if (rk < 12) dev_inproj(a, g, rk, smem);
    bar();

    for (int l = 0; l < DEPTH; ++l) {
        if (rk < 48) dev_gemm<0>(a, l, g, rk, smem);
        bar();
        if (rk < 32) dev_bc(a, l, g, rk, smem);
        bar();
        if (rk < 12) dev_gemm<1>(a, l, g, rk, smem);
        bar();
    }
    dev_ln(a, g, rk, smem);
}

// ================= fallback wrappers (multi-kernel, r8-equivalent) ==========
__global__ __launch_bounds__(NTHREADS) void k_inproj(Args a) {
    __shared__ __align__(16) char smem[32768];
    dev_inproj(a, blockIdx.x / 12, blockIdx.x % 12, smem);
}
__global__ __launch_bounds__(NTHREADS) void k_xz(Args a, int l) {
    __shared__ __align__(16) char smem[32768];
    dev_gemm<0>(a, l, blockIdx.x / 48, blockIdx.x % 48, smem);
}
__global__ __launch_bounds__(NTHREADS) void k_bc(Args a, int l) {
    __shared__ __align__(16) char smem[32768];
    dev_bc(a, l, blockIdx.x / 32, blockIdx.x % 32, smem);
}
__global__ __launch_bounds__(NTHREADS) void k_op(Args a, int l) {
    __shared__ __align__(16) char smem[32768];
    dev_gemm<1>(a, l, blockIdx.x / 12, blockIdx.x % 12, smem);
}
__global__ __launch_bounds__(NTHREADS) void k_ln(Args a) {
    __shared__ __align__(16) char smem[32768];
    dev_ln(a, blockIdx.x / 64, blockIdx.x % 64, smem);
}

extern "C" void kernel_launch(void* const* d_in, const int* in_sizes, int n_in,
                              void* d_out, int out_size, void* d_ws, size_t ws_size,
                              hipStream_t stream)
{
    char* wsb = (char*)d_ws;
    unsigned* ctr = (unsigned*)wsb;                        // CTR_TOTAL u32 (~70KB)
    float* h    = (float*)(wsb + ((CTR_TOTAL * 4 + 255) & ~255));
    float* x    = h + (size_t)BATCH * D_MODEL;
    float* g    = x + (size_t)BATCH * D_INNER;
    float* Aneg = g + (size_t)BATCH * D_INNER;
    ushort_t* h_hi = (ushort_t*)(Aneg + (size_t)DEPTH * D_INNER * D_STATE);
    ushort_t* h_lo = h_hi + (size_t)BATCH * D_MODEL;
    ushort_t* y_hi = h_lo + (size_t)BATCH * D_MODEL;
    ushort_t* y_lo = y_hi + (size_t)BATCH * D_INNER;
    ushort_t* xzw_hi = y_lo + (size_t)BATCH * D_INNER;
    ushort_t* xzw_lo = xzw_hi + (size_t)DEPTH * XZW_N;
    ushort_t* opw_hi = xzw_lo + (size_t)DEPTH * XZW_N;
    ushort_t* opw_lo = opw_hi + (size_t)DEPTH * OPW_N;

    Args args;
    args.x_t        = (const float*)d_in[0];
    args.in_w       = (const float*)d_in[1];
    args.in_b       = (const float*)d_in[2];
    const float* xz_w      = (const float*)d_in[3];
    args.conv_w     = (const float*)d_in[4];
    args.conv_b     = (const float*)d_in[5];
    args.xproj_w    = (const float*)d_in[6];
    args.dtproj_w   = (const float*)d_in[7];
    args.dtproj_b   = (const float*)d_in[8];
    const float* A_log     = (const float*)d_in[9];
    args.Dvec       = (const float*)d_in[10];
    const float* outproj_w = (const float*)d_in[11];
    args.conv_state = (const float*)d_in[12];
    args.ssm_state  = (const float*)d_in[13];
    args.ln_g       = (const float*)d_in[14];
    args.ln_b       = (const float*)d_in[15];
    args.h = h; args.x = x; args.g = g; args.Aneg = Aneg;
    args.out = (float*)d_out;
    args.h_hi = h_hi; args.h_lo = h_lo; args.y_hi = y_hi; args.y_lo = y_lo;
    args.xzw_hi = xzw_hi; args.xzw_lo = xzw_lo;
    args.opw_hi = opw_hi; args.opw_lo = opw_lo;
    args.ctr = ctr;

    dim3 blk(NTHREADS);

    k_init<<<dim3((CTR_TOTAL + 255) / 256), blk, 0, stream>>>(ctr);
    k_prep<<<dim3(2048), blk, 0, stream>>>(
        xz_w, outproj_w, A_log, xzw_hi, xzw_lo, opw_hi, opw_lo, Aneg);

    void* kp[] = { &args };
    hipError_t e = hipLaunchCooperativeKernel((const void*)persist, dim3(GRID),
                                              dim3(NTHREADS), kp, 0, stream);
    if (e != hipSuccess) {
        (void)hipGetLastError();  // clear; fall back to proven multi-kernel path
        k_inproj<<<dim3(96), blk, 0, stream>>>(args);
        for (int l = 0; l < DEPTH; ++l) {
            k_xz<<<dim3(384), blk, 0, stream>>>(args, l);
            k_bc<<<dim3(256), blk, 0, stream>>>(args, l);
            k_op<<<dim3(96), blk, 0, stream>>>(args, l);
        }
        k_ln<<<dim3(512), blk, 0, stream>>>(args);
    }
}

// Round 11
// 3098.234 us; speedup vs baseline: 1.2996x; 1.2847x over previous
//
#include <hip/hip_runtime.h>
#include <cstdint>
#include <cstddef>

#define BATCH 512
#define D_IN 64
#define D_MODEL 768
#define DEPTH 24
#define D_INNER 1536
#define D_STATE 16
#define D_CONV 4
#define DT_RANK 48
#define XDB_DIM 80

typedef __bf16 bf16x8 __attribute__((ext_vector_type(8)));
typedef unsigned short ushortx8 __attribute__((ext_vector_type(8)));
typedef float f32x4 __attribute__((ext_vector_type(4)));
typedef unsigned short ushort_t;

#define XZW_N ((size_t)2 * D_INNER * D_MODEL)   // per-layer xz_w elems
#define OPW_N ((size_t)D_MODEL * D_INNER)       // per-layer outproj_w elems

__device__ __forceinline__ float sigmoidf_(float v) { return 1.f / (1.f + __expf(-v)); }

// Truncation-based fp32 -> bf16 hi/lo split (bit-identical to rounds 2-10).
__device__ __forceinline__ void split1(float f, unsigned short& h, unsigned short& l) {
    unsigned int u = __float_as_uint(f);
    unsigned int uh = u & 0xffff0000u;
    h = (unsigned short)(uh >> 16);
    float r = f - __uint_as_float(uh);
    l = (unsigned short)(__float_as_uint(r) >> 16);
}

// Fragment-linear plane layout: [K/32][Mtot/16] blocks of 512 shorts (1KB).
// Within a block: lane l of a wave holds bytes [l*16, l*16+16) = elem
// (row = l&15, k-chunk = l>>4). So an MFMA operand fragment is ONE fully
// coalesced wave-linear 1KB load — no LDS, no staging, no barriers.
__device__ __forceinline__ size_t fl_idx(int row, int k, int Mtot) {
    return ((size_t)(k >> 5) * (Mtot >> 4) + (row >> 4)) * 512
         + (size_t)(((k >> 3) & 3) << 7) + ((row & 15) << 3) + (k & 7);
}

// ---- one-time: split ALL layers' weights into frag-linear bf16 hi/lo planes
// and precompute Aneg = -exp(A_log). ~680MB streamed.
__global__ __launch_bounds__(256) void k_prep(
    const float* __restrict__ xz_w, const float* __restrict__ op_w,
    const float* __restrict__ A_log,
    ushort_t* __restrict__ xzw_hi, ushort_t* __restrict__ xzw_lo,
    ushort_t* __restrict__ opw_hi, ushort_t* __restrict__ opw_lo,
    float* __restrict__ Aneg)
{
    const long XZ_ALL = (long)DEPTH * (long)(XZW_N / 8);
    const long OP_ALL = (long)DEPTH * (long)(OPW_N / 8);
    const long AN_ALL = (long)DEPTH * D_INNER * D_STATE / 8;
    const long total = XZ_ALL + OP_ALL + AN_ALL;
    long g = (long)blockIdx.x * 256 + threadIdx.x;
    const long stride = (long)gridDim.x * 256;
    for (; g < total; g += stride) {
        if (g < XZ_ALL) {
            const int l = (int)(g / (XZW_N / 8));
            const long gl = (g - (long)l * (XZW_N / 8)) * 8;
            const int n = (int)(gl / D_MODEL), k0 = (int)(gl % D_MODEL);
            const float* s = xz_w + (size_t)l * XZW_N + gl;
            const size_t dst = (size_t)l * XZW_N + fl_idx(n, k0, 2 * D_INNER);
            float4 A4 = *(const float4*)s;
            float4 B4 = *(const float4*)(s + 4);
            float f[8] = {A4.x, A4.y, A4.z, A4.w, B4.x, B4.y, B4.z, B4.w};
            ushortx8 h, lo;
#pragma unroll
            for (int j = 0; j < 8; ++j) { unsigned short hh, ll; split1(f[j], hh, ll); h[j] = hh; lo[j] = ll; }
            *(ushortx8*)(xzw_hi + dst) = h;
            *(ushortx8*)(xzw_lo + dst) = lo;
        } else if (g < XZ_ALL + OP_ALL) {
            const long r = g - XZ_ALL;
            const int l = (int)(r / (OPW_N / 8));
            const long gl = (r - (long)l * (OPW_N / 8)) * 8;
            const int n = (int)(gl / D_INNER), k0 = (int)(gl % D_INNER);
            const float* s = op_w + (size_t)l * OPW_N + gl;
            const size_t dst = (size_t)l * OPW_N + fl_idx(n, k0, D_MODEL);
            float4 A4 = *(const float4*)s;
            float4 B4 = *(const float4*)(s + 4);
            float f[8] = {A4.x, A4.y, A4.z, A4.w, B4.x, B4.y, B4.z, B4.w};
            ushortx8 h, lo;
#pragma unroll
            for (int j = 0; j < 8; ++j) { unsigned short hh, ll; split1(f[j], hh, ll); h[j] = hh; lo[j] = ll; }
            *(ushortx8*)(opw_hi + dst) = h;
            *(ushortx8*)(opw_lo + dst) = lo;
        } else {
            const long r = g - XZ_ALL - OP_ALL;
            const float* s = A_log + r * 8;
            float* d = Aneg + r * 8;
#pragma unroll
            for (int j = 0; j < 8; ++j) d[j] = -__expf(s[j]);
        }
    }
}

// ---- in_proj fp32 GEMM (M=512,N=768,K=64) -> h frag-linear planes
__global__ __launch_bounds__(256) void k_inproj(
    const float* __restrict__ A, const float* __restrict__ W,
    const float* __restrict__ bias,
    ushort_t* __restrict__ Chi, ushort_t* __restrict__ Clo)
{
    __shared__ float As[16][68];
    __shared__ float Ws[16][68];
    const int tid = threadIdx.x;
    const int tx = tid & 15, ty = tid >> 4;
    const int bn0 = blockIdx.x * 64, bm0 = blockIdx.y * 64;
    float acc[4][4] = {};
    for (int k0 = 0; k0 < D_IN; k0 += 16) {
        int r = tid >> 2, c = (tid & 3) << 2;
        float4 a4 = *(const float4*)(A + (size_t)(bm0 + r) * D_IN + k0 + c);
        As[c + 0][r] = a4.x; As[c + 1][r] = a4.y;
        As[c + 2][r] = a4.z; As[c + 3][r] = a4.w;
        float4 w4 = *(const float4*)(W + (size_t)(bn0 + r) * D_IN + k0 + c);
        Ws[c + 0][r] = w4.x; Ws[c + 1][r] = w4.y;
        Ws[c + 2][r] = w4.z; Ws[c + 3][r] = w4.w;
        __syncthreads();
#pragma unroll
        for (int kk = 0; kk < 16; ++kk) {
            float af[4], wf[4];
#pragma unroll
            for (int i = 0; i < 4; ++i) af[i] = As[kk][ty * 4 + i];
#pragma unroll
            for (int j = 0; j < 4; ++j) wf[j] = Ws[kk][tx * 4 + j];
#pragma unroll
            for (int i = 0; i < 4; ++i)
#pragma unroll
                for (int j = 0; j < 4; ++j) acc[i][j] += af[i] * wf[j];
        }
        __syncthreads();
    }
#pragma unroll
    for (int i = 0; i < 4; ++i) {
        const int bb = bm0 + ty * 4 + i;
#pragma unroll
        for (int j = 0; j < 4; ++j) {
            const int n = bn0 + tx * 4 + j;
            float v = acc[i][j] + bias[n];
            unsigned short hh, ll;
            split1(v, hh, ll);
            const size_t idx = fl_idx(bb, n, BATCH);
            Chi[idx] = hh;
            Clo[idx] = ll;
        }
    }
}

// ---- no-LDS bf16x3 MFMA GEMM. 64x64 tile, 4 waves of 32x32 (2x2 frags of
// 16x16x32). Operands load directly from frag-linear planes as coalesced
// wave-linear 1KB reads (L2/L3-served). No LDS, no __syncthreads.
// XCD-aware block map keeps each W eighth resident in one XCD's L2.
// MODE 0: xz (K=768, 384 blocks) + conv/silu epilogue -> x, g (linear fp32)
// MODE 1: outproj (K=1536, 96 blocks) -> h fp32 + h frag-planes
template<int MODE>
__global__ __launch_bounds__(256) void k_gemm(
    const ushort_t* __restrict__ Ahi, const ushort_t* __restrict__ Alo,
    const ushort_t* __restrict__ Whi, const ushort_t* __restrict__ Wlo,
    float* __restrict__ xout, float* __restrict__ gout,
    float* __restrict__ hout, ushort_t* __restrict__ Chi, ushort_t* __restrict__ Clo,
    const float* __restrict__ conv_state, const float* __restrict__ conv_w,
    const float* __restrict__ conv_b)
{
    constexpr int K = (MODE == 0) ? D_MODEL : D_INNER;
    constexpr int NK = K / 32;
    constexpr int NT = (MODE == 0) ? 2 * D_INNER : D_MODEL;
    constexpr size_t ASTEP = (size_t)(BATCH >> 4) * 512;   // A frag-row count per k-step
    constexpr size_t WSTEP = (size_t)(NT >> 4) * 512;      // W frag-row count per k-step

    const int bid = blockIdx.x;
    int c, r;
    if (MODE == 0) {             // 48 col-tiles x 8 row-tiles; XCD = bid&7 owns c%8
        c = (bid & 7) + ((bid >> 6) << 3);
        r = (bid >> 3) & 7;
    } else {                     // 12 col-tiles x 8 row-tiles
        if (bid < 64) { c = bid & 7; r = bid >> 3; }
        else { const int j = bid - 64; c = 8 + (j & 3); r = j >> 2; }
    }
    const int bn0 = c * 64, bm0 = r * 64;

    const int t = threadIdx.x;
    const int lane = t & 63, wv = t >> 6;
    const int wm = wv >> 1, wn = wv & 1;
    const int ln15 = lane & 15, kq = lane >> 4;

    // per-wave fragment base pointers (frag-linear: +512 shorts per +16 rows)
    const size_t aoff = (size_t)((bm0 + wm * 32) >> 4) * 512 + lane * 8;
    const size_t woff = (size_t)((bn0 + wn * 32) >> 4) * 512 + lane * 8;
    const ushort_t* pah = Ahi + aoff;
    const ushort_t* pal = Alo + aoff;
    const ushort_t* pwh = Whi + woff;
    const ushort_t* pwl = Wlo + woff;

    f32x4 acc[2][2];
#pragma unroll
    for (int m = 0; m < 2; ++m)
#pragma unroll
        for (int n = 0; n < 2; ++n) acc[m][n] = (f32x4){0.f, 0.f, 0.f, 0.f};

#pragma unroll 2
    for (int ks = 0; ks < NK; ++ks) {
        bf16x8 ah[2], al[2], bh[2], bl[2];
#pragma unroll
        for (int m = 0; m < 2; ++m) {
            ah[m] = __builtin_bit_cast(bf16x8, *(const ushortx8*)(pah + ks * ASTEP + m * 512));
            al[m] = __builtin_bit_cast(bf16x8, *(const ushortx8*)(pal + ks * ASTEP + m * 512));
        }
#pragma unroll
        for (int n = 0; n < 2; ++n) {
            bh[n] = __builtin_bit_cast(bf16x8, *(const ushortx8*)(pwh + ks * WSTEP + n * 512));
            bl[n] = __builtin_bit_cast(bf16x8, *(const ushortx8*)(pwl + ks * WSTEP + n * 512));
        }
#pragma unroll
        for (int m = 0; m < 2; ++m)
#pragma unroll
            for (int n = 0; n < 2; ++n) {
                acc[m][n] = __builtin_amdgcn_mfma_f32_16x16x32_bf16(ah[m], bh[n], acc[m][n], 0, 0, 0);
                acc[m][n] = __builtin_amdgcn_mfma_f32_16x16x32_bf16(ah[m], bl[n], acc[m][n], 0, 0, 0);
                acc[m][n] = __builtin_amdgcn_mfma_f32_16x16x32_bf16(al[m], bh[n], acc[m][n], 0, 0, 0);
            }
    }

    // epilogue: C/D frag mapping col=lane&15, row=(lane>>4)*4+j
#pragma unroll
    for (int m = 0; m < 2; ++m) {
#pragma unroll
        for (int n = 0; n < 2; ++n) {
            const int col = bn0 + wn * 32 + n * 16 + ln15;
            const int row0 = bm0 + wm * 32 + m * 16 + kq * 4;
            f32x4 v = acc[m][n];
            if (MODE == 0) {
                if (col < D_INNER) {
                    const float4 cwv = *(const float4*)(conv_w + (size_t)col * 4);
                    const float cbv = conv_b[col];
#pragma unroll
                    for (int j = 0; j < 4; ++j) {
                        const int row = row0 + j;
                        const float4 csv = *(const float4*)(conv_state + ((size_t)row * D_INNER + col) * 4);
                        float cc = csv.y * cwv.x + csv.z * cwv.y + csv.w * cwv.z
                                 + v[j] * cwv.w + cbv;
                        xout[(size_t)row * D_INNER + col] = cc * sigmoidf_(cc);
                    }
                } else {
#pragma unroll
                    for (int j = 0; j < 4; ++j) {
                        float zv = v[j];
                        gout[(size_t)(row0 + j) * D_INNER + (col - D_INNER)] = zv * sigmoidf_(zv);
                    }
                }
            } else {
#pragma unroll
                for (int j = 0; j < 4; ++j) {
                    float val = v[j];
                    hout[(size_t)(row0 + j) * D_MODEL + col] = val;
                    unsigned short hh, ll;
                    split1(val, hh, ll);
                    const size_t idx = fl_idx(row0 + j, col, BATCH);
                    Chi[idx] = hh;
                    Clo[idx] = ll;
                }
            }
        }
    }
}

// ---- fused xproj + dt + softplus + SSM + gate; 2 batch rows per block;
// writes y planes in frag-linear layout (A-operand of outproj).
__global__ __launch_bounds__(256) void k_bc(
    const float* __restrict__ x, const float* __restrict__ g,
    const float* __restrict__ xproj_w, const float* __restrict__ dtproj_w,
    const float* __restrict__ dtproj_b, const float* __restrict__ Aneg_l,
    const float* __restrict__ Dp, const float* __restrict__ ssm,
    ushort_t* __restrict__ yhi, ushort_t* __restrict__ ylo)
{
    __shared__ __align__(16) float xs0[D_INNER];
    __shared__ __align__(16) float xs1[D_INNER];
    __shared__ float xdb0[XDB_DIM];
    __shared__ float xdb1[XDB_DIM];
    const int tid = threadIdx.x;
    const int b0 = blockIdx.x * 2, b1 = b0 + 1;

    {
        const float4* xr0 = (const float4*)(x + (size_t)b0 * D_INNER);
        const float4* xr1 = (const float4*)(x + (size_t)b1 * D_INNER);
        float4* d0 = (float4*)xs0; float4* d1 = (float4*)xs1;
        for (int i = tid; i < D_INNER / 4; i += 256) { d0[i] = xr0[i]; d1[i] = xr1[i]; }
    }
    __syncthreads();

    const int lane = tid & 63, wv = tid >> 6;
    const float4* xs40 = (const float4*)xs0;
    const float4* xs41 = (const float4*)xs1;
    for (int n = wv; n < XDB_DIM; n += 4) {
        const float4* wr = (const float4*)(xproj_w + (size_t)n * D_INNER);
        float s0 = 0.f, s1 = 0.f;
#pragma unroll
        for (int j = 0; j < D_INNER / 4 / 64; ++j) {
            float4 w = wr[lane + 64 * j];
            float4 u = xs40[lane + 64 * j];
            float4 q = xs41[lane + 64 * j];
            s0 += w.x * u.x + w.y * u.y + w.z * u.z + w.w * u.w;
            s1 += w.x * q.x + w.y * q.y + w.z * q.z + w.w * q.w;
        }
#pragma unroll
        for (int off = 32; off > 0; off >>= 1) { s0 += __shfl_xor(s0, off); s1 += __shfl_xor(s1, off); }
        if (lane == 0) { xdb0[n] = s0; xdb1[n] = s1; }
    }
    __syncthreads();

    float B0[16], C0[16], B1[16], C1[16];
#pragma unroll
    for (int n = 0; n < 16; ++n) {
        B0[n] = xdb0[DT_RANK + n]; C0[n] = xdb0[DT_RANK + 16 + n];
        B1[n] = xdb1[DT_RANK + n]; C1[n] = xdb1[DT_RANK + 16 + n];
    }

    for (int d = tid; d < D_INNER; d += 256) {
        const float4* dtw = (const float4*)(dtproj_w + (size_t)d * DT_RANK);
        float s0 = 0.f, s1 = 0.f;
#pragma unroll
        for (int j = 0; j < DT_RANK / 4; ++j) {
            float4 w = dtw[j];
            s0 += w.x * xdb0[4*j] + w.y * xdb0[4*j+1] + w.z * xdb0[4*j+2] + w.w * xdb0[4*j+3];
            s1 += w.x * xdb1[4*j] + w.y * xdb1[4*j+1] + w.z * xdb1[4*j+2] + w.w * xdb1[4*j+3];
        }
        const float bb = dtproj_b[d];
        s0 += bb; s1 += bb;
        float dt0 = fmaxf(s0, 0.f) + log1pf(__expf(-fabsf(s0)));
        float dt1 = fmaxf(s1, 0.f) + log1pf(__expf(-fabsf(s1)));
        const float xv0 = xs0[d], xv1 = xs1[d];
        const float dtx0 = dt0 * xv0, dtx1 = dt1 * xv1;
        const float4* anp = (const float4*)(Aneg_l + (size_t)d * D_STATE);
        const float4* sp0 = (const float4*)(ssm + ((size_t)b0 * D_INNER + d) * D_STATE);
        const float4* sp1 = (const float4*)(ssm + ((size_t)b1 * D_INNER + d) * D_STATE);
        float y0 = 0.f, y1 = 0.f;
#pragma unroll
        for (int q = 0; q < 4; ++q) {
            float4 an = anp[q];
            float4 u = sp0[q];
            float4 w = sp1[q];
            float e;
            e = __expf(dt0 * an.x); y0 += (u.x * e + dtx0 * B0[4*q+0]) * C0[4*q+0];
            e = __expf(dt0 * an.y); y0 += (u.y * e + dtx0 * B0[4*q+1]) * C0[4*q+1];
            e = __expf(dt0 * an.z); y0 += (u.z * e + dtx0 * B0[4*q+2]) * C0[4*q+2];
            e = __expf(dt0 * an.w); y0 += (u.w * e + dtx0 * B0[4*q+3]) * C0[4*q+3];
            e = __expf(dt1 * an.x); y1 += (w.x * e + dtx1 * B1[4*q+0]) * C1[4*q+0];
            e = __expf(dt1 * an.y); y1 += (w.y * e + dtx1 * B1[4*q+1]) * C1[4*q+1];
            e = __expf(dt1 * an.z); y1 += (w.z * e + dtx1 * B1[4*q+2]) * C1[4*q+2];
            e = __expf(dt1 * an.w); y1 += (w.w * e + dtx1 * B1[4*q+3]) * C1[4*q+3];
        }
        const float dv = Dp[d];
        y0 += dv * xv0; y1 += dv * xv1;
        const float o0 = y0 * g[(size_t)b0 * D_INNER + d];
        const float o1 = y1 * g[(size_t)b1 * D_INNER + d];
        unsigned short hh, ll;
        split1(o0, hh, ll);
        const size_t i0 = fl_idx(b0, d, BATCH);
        yhi[i0] = hh; ylo[i0] = ll;
        split1(o1, hh, ll);
        const size_t i1 = fl_idx(b1, d, BATCH);
        yhi[i1] = hh; ylo[i1] = ll;
    }
}

// ---- LayerNorm, one block per row
__global__ __launch_bounds__(256) void k_ln(
    const float* __restrict__ h, const float* __restrict__ gam,
    const float* __restrict__ bet, float* __restrict__ out)
{
    const int b = blockIdx.x;
    const int tid = threadIdx.x;
    float v[3];
#pragma unroll
    for (int j = 0; j < 3; ++j) v[j] = h[(size_t)b * D_MODEL + tid + j * 256];
    float s = v[0] + v[1] + v[2];
    float s2 = v[0] * v[0] + v[1] * v[1] + v[2] * v[2];
#pragma unroll
    for (int off = 32; off > 0; off >>= 1) {
        s += __shfl_xor(s, off);
        s2 += __shfl_xor(s2, off);
    }
    __shared__ float red[8];
    const int lane = tid & 63, wv = tid >> 6;
    if (lane == 0) { red[wv] = s; red[4 + wv] = s2; }
    __syncthreads();
    s = red[0] + red[1] + red[2] + red[3];
    s2 = red[4] + red[5] + red[6] + red[7];
    const float mu = s * (1.f / D_MODEL);
    const float var = s2 * (1.f / D_MODEL) - mu * mu;
    const float inv = 1.f / sqrtf(var + 1e-5f);
#pragma unroll
    for (int j = 0; j < 3; ++j) {
        int c = tid + j * 256;
        out[(size_t)b * D_MODEL + c] = (v[j] - mu) * inv * gam[c] + bet[c];
    }
}

extern "C" void kernel_launch(void* const* d_in, const int* in_sizes, int n_in,
                              void* d_out, int out_size, void* d_ws, size_t ws_size,
                              hipStream_t stream)
{
    const float* x_t        = (const float*)d_in[0];
    const float* in_w       = (const float*)d_in[1];
    const float* in_b       = (const float*)d_in[2];
    const float* xz_w       = (const float*)d_in[3];
    const float* conv_w     = (const float*)d_in[4];
    const float* conv_b     = (const float*)d_in[5];
    const float* xproj_w    = (const float*)d_in[6];
    const float* dtproj_w   = (const float*)d_in[7];
    const float* dtproj_b   = (const float*)d_in[8];
    const float* A_log      = (const float*)d_in[9];
    const float* Dvec       = (const float*)d_in[10];
    const float* outproj_w  = (const float*)d_in[11];
    const float* conv_state = (const float*)d_in[12];
    const float* ssm_state  = (const float*)d_in[13];
    const float* ln_g       = (const float*)d_in[14];
    const float* ln_b       = (const float*)d_in[15];

    float* ws = (float*)d_ws;
    float* h    = ws;                                // 512*768
    float* x    = h + (size_t)BATCH * D_MODEL;       // 512*1536
    float* g    = x + (size_t)BATCH * D_INNER;       // 512*1536 (silu-gated z)
    float* Aneg = g + (size_t)BATCH * D_INNER;       // 24*1536*16
    ushort_t* h_hi = (ushort_t*)(Aneg + (size_t)DEPTH * D_INNER * D_STATE);
    ushort_t* h_lo = h_hi + (size_t)BATCH * D_MODEL;
    ushort_t* y_hi = h_lo + (size_t)BATCH * D_MODEL;
    ushort_t* y_lo = y_hi + (size_t)BATCH * D_INNER;
    ushort_t* xzw_hi = y_lo + (size_t)BATCH * D_INNER;
    ushort_t* xzw_lo = xzw_hi + (size_t)DEPTH * XZW_N;
    ushort_t* opw_hi = xzw_lo + (size_t)DEPTH * XZW_N;
    ushort_t* opw_lo = opw_hi + (size_t)DEPTH * OPW_N;

    dim3 blk(256);

    k_prep<<<dim3(2048), blk, 0, stream>>>(
        xz_w, outproj_w, A_log, xzw_hi, xzw_lo, opw_hi, opw_lo, Aneg);

    k_inproj<<<dim3(12, 8), blk, 0, stream>>>(x_t, in_w, in_b, h_hi, h_lo);

    for (int l = 0; l < DEPTH; ++l) {
        const ushort_t* xzh = xzw_hi + (size_t)l * XZW_N;
        const ushort_t* xzl = xzw_lo + (size_t)l * XZW_N;
        const ushort_t* oph = opw_hi + (size_t)l * OPW_N;
        const ushort_t* opl = opw_lo + (size_t)l * OPW_N;
        const float* csl = conv_state + (size_t)l * BATCH * D_INNER * D_CONV;
        const float* cwl = conv_w + (size_t)l * D_INNER * D_CONV;
        const float* cbl = conv_b + (size_t)l * D_INNER;
        const float* xpl = xproj_w + (size_t)l * XDB_DIM * D_INNER;
        const float* dwl = dtproj_w + (size_t)l * D_INNER * DT_RANK;
        const float* dbl = dtproj_b + (size_t)l * D_INNER;
        const float* anl = Aneg + (size_t)l * D_INNER * D_STATE;
        const float* dpl = Dvec + (size_t)l * D_INNER;
        const float* ssl = ssm_state + (size_t)l * BATCH * D_INNER * D_STATE;

        k_gemm<0><<<dim3(384), blk, 0, stream>>>(
            h_hi, h_lo, xzh, xzl, x, g, nullptr, nullptr, nullptr,
            csl, cwl, cbl);

        k_bc<<<dim3(256), blk, 0, stream>>>(
            x, g, xpl, dwl, dbl, anl, dpl, ssl, y_hi, y_lo);

        k_gemm<1><<<dim3(96), blk, 0, stream>>>(
            y_hi, y_lo, oph, opl, nullptr, nullptr, h, h_hi, h_lo,
            nullptr, nullptr, nullptr);
    }

    k_ln<<<dim3(BATCH), blk, 0, stream>>>(h, ln_g, ln_b, (float*)d_out);
}